// Round 3
// baseline (1111.343 us; speedup 1.0000x reference)
//
#include <hip/hip_runtime.h>
#include <math.h>

// ---------------------------------------------------------------------------
// GCN 2-layer: per layer  out = Ahat @ (x @ W) + b, then erf-GELU.
// Ahat built from edge list with self-loops and symmetric rsqrt-degree norm.
// Strategy: build CSR by dst on device each call (counting sort), compute
// dinv once, then per layer: tiled fp32 GEMM -> per-node gather-reduce+GELU.
// Layer-1 activations live in d_out to halve workspace use (~66 MB total).
// ---------------------------------------------------------------------------

#define HID 128

__global__ __launch_bounds__(256) void init_deg_kernel(float* deg, int* count, int n) {
    int i = blockIdx.x * 256 + threadIdx.x;
    if (i < n) { deg[i] = 1.0f; count[i] = 0; }
}

__global__ __launch_bounds__(256) void count_deg_kernel(const int* __restrict__ dst,
                                                        const float* __restrict__ w,
                                                        float* __restrict__ deg,
                                                        int* __restrict__ count, int E) {
    int e = blockIdx.x * 256 + threadIdx.x;
    if (e < E) {
        int d = dst[e];
        atomicAdd(&deg[d], w[e]);
        atomicAdd(&count[d], 1);
    }
}

// Hillis-Steele exclusive scan, 1024/block. scan1 writes per-block exclusive
// values + block totals; scan2 scans the totals; finalize adds offsets.
__global__ __launch_bounds__(1024) void scan1_kernel(const int* __restrict__ count,
                                                     int* __restrict__ row_start,
                                                     int* __restrict__ partials, int n) {
    __shared__ int sdata[1024];
    int t = threadIdx.x;
    int gid = blockIdx.x * 1024 + t;
    int v = (gid < n) ? count[gid] : 0;
    sdata[t] = v;
    __syncthreads();
    for (int off = 1; off < 1024; off <<= 1) {
        int x = (t >= off) ? sdata[t - off] : 0;
        __syncthreads();
        sdata[t] += x;
        __syncthreads();
    }
    if (gid < n) row_start[gid] = sdata[t] - v;  // exclusive
    if (t == 1023) partials[blockIdx.x] = sdata[t];
}

__global__ __launch_bounds__(1024) void scan2_kernel(int* partials, int nparts) {
    __shared__ int sdata[1024];
    int t = threadIdx.x;
    int v = (t < nparts) ? partials[t] : 0;
    sdata[t] = v;
    __syncthreads();
    for (int off = 1; off < 1024; off <<= 1) {
        int x = (t >= off) ? sdata[t - off] : 0;
        __syncthreads();
        sdata[t] += x;
        __syncthreads();
    }
    if (t < nparts) partials[t] = sdata[t] - v;  // exclusive
}

__global__ __launch_bounds__(256) void finalize_kernel(const int* __restrict__ partials,
                                                       int* __restrict__ row_start,
                                                       float* __restrict__ deg,  // in: deg, out: dinv
                                                       int* __restrict__ cursor, int n, int E) {
    int i = blockIdx.x * 256 + threadIdx.x;
    if (i < n) {
        row_start[i] += partials[i >> 10];
        cursor[i] = 0;
        deg[i] = rsqrtf(deg[i]);  // deg >= 1 always (self loop), no zero guard needed
    }
    if (i == 0) row_start[n] = E;
}

__global__ __launch_bounds__(256) void fill_csr_kernel(const int* __restrict__ src,
                                                       const int* __restrict__ dst,
                                                       const float* __restrict__ w,
                                                       const int* __restrict__ row_start,
                                                       int* __restrict__ cursor,
                                                       const float* __restrict__ dinv,
                                                       int* __restrict__ csr_src,
                                                       float* __restrict__ csr_norm, int E) {
    int e = blockIdx.x * 256 + threadIdx.x;
    if (e >= E) return;
    int s = src[e], d = dst[e];
    float nw = dinv[s] * w[e] * dinv[d];
    int pos = row_start[d] + atomicAdd(&cursor[d], 1);
    csr_src[pos] = s;
    csr_norm[pos] = nw;
}

// ---------------------------------------------------------------------------
// GEMM: H[n][128] = A[n][K] @ W[K][128], fp32. Tile 64 rows x 128 cols,
// K-chunk 32. 256 threads: 32 col-groups (4 cols each) x 8 row-groups
// (8 rows each, stride 8). acc[8][4] per thread.
// ---------------------------------------------------------------------------
template <int K>
__global__ __launch_bounds__(256) void gemm_kernel(const float* __restrict__ A,
                                                   const float* __restrict__ W,
                                                   float* __restrict__ H, int n) {
    __shared__ float xs[64][36];    // pad 36 -> bank-spread
    __shared__ float ws[32][128];
    const int t = threadIdx.x;
    const int block_row = blockIdx.x * 64;
    const int tc = t & 31;   // cols 4*tc .. 4*tc+3
    const int tr = t >> 5;   // rows tr, tr+8, ..., tr+56

    float acc[8][4];
#pragma unroll
    for (int i = 0; i < 8; i++)
#pragma unroll
        for (int j = 0; j < 4; j++) acc[i][j] = 0.f;

    for (int k0 = 0; k0 < K; k0 += 32) {
        // load A tile: 64 x 32 floats = 512 float4, 2 per thread
#pragma unroll
        for (int i = 0; i < 2; i++) {
            int idx = i * 256 + t;        // 0..511
            int r = idx >> 3;             // 8 float4 per row
            int c4 = idx & 7;
            float4 v = make_float4(0.f, 0.f, 0.f, 0.f);
            int gr = block_row + r;
            if (gr < n) v = *reinterpret_cast<const float4*>(&A[(size_t)gr * K + k0 + c4 * 4]);
            *reinterpret_cast<float4*>(&xs[r][c4 * 4]) = v;
        }
        // load W tile: 32 x 128 floats = 1024 float4, 4 per thread
#pragma unroll
        for (int i = 0; i < 4; i++) {
            int idx = i * 256 + t;        // 0..1023
            int r = idx >> 5;             // 32 float4 per row
            int c4 = idx & 31;
            float4 v = *reinterpret_cast<const float4*>(&W[(size_t)(k0 + r) * 128 + c4 * 4]);
            *reinterpret_cast<float4*>(&ws[r][c4 * 4]) = v;
        }
        __syncthreads();
#pragma unroll
        for (int kk = 0; kk < 32; kk++) {
            float wv[4];
            *reinterpret_cast<float4*>(wv) = *reinterpret_cast<const float4*>(&ws[kk][tc * 4]);
#pragma unroll
            for (int i = 0; i < 8; i++) {
                float xv = xs[tr + i * 8][kk];
                acc[i][0] += xv * wv[0];
                acc[i][1] += xv * wv[1];
                acc[i][2] += xv * wv[2];
                acc[i][3] += xv * wv[3];
            }
        }
        __syncthreads();
    }
#pragma unroll
    for (int i = 0; i < 8; i++) {
        int gr = block_row + tr + i * 8;
        if (gr < n) {
            float4 v = make_float4(acc[i][0], acc[i][1], acc[i][2], acc[i][3]);
            *reinterpret_cast<float4*>(&H[(size_t)gr * 128 + tc * 4]) = v;
        }
    }
}

// ---------------------------------------------------------------------------
// Aggregate + bias + erf-GELU. 2 nodes per 256-thread block, 1 dim/thread.
// out[v][c] = gelu( b[c] + dinv[v]^2 * h[v][c] + sum_e norm_e * h[src_e][c] )
// ---------------------------------------------------------------------------
__global__ __launch_bounds__(256) void aggregate_gelu_kernel(const float* __restrict__ h,
                                                             const int* __restrict__ row_start,
                                                             const int* __restrict__ csr_src,
                                                             const float* __restrict__ csr_norm,
                                                             const float* __restrict__ dinv,
                                                             const float* __restrict__ bias,
                                                             float* __restrict__ out, int n) {
    int node = blockIdx.x * 2 + (threadIdx.x >> 7);
    int c = threadIdx.x & 127;
    if (node >= n) return;
    float di = dinv[node];
    float acc = bias[c] + di * di * h[(size_t)node * 128 + c];
    int e0 = row_start[node], e1 = row_start[node + 1];
    for (int e = e0; e < e1; e++) {
        int s = csr_src[e];
        float w = csr_norm[e];
        acc += w * h[(size_t)s * 128 + c];
    }
    float g = 0.5f * acc * (1.0f + erff(acc * 0.70710678118654752f));
    out[(size_t)node * 128 + c] = g;
}

// ---------------------------------------------------------------------------

extern "C" void kernel_launch(void* const* d_in, const int* in_sizes, int n_in,
                              void* d_out, int out_size, void* d_ws, size_t ws_size,
                              hipStream_t stream) {
    const float* x  = (const float*)d_in[0];
    const int*   ei = (const int*)d_in[1];
    const float* ew = (const float*)d_in[2];
    const float* W1 = (const float*)d_in[3];
    const float* b1 = (const float*)d_in[4];
    const float* W2 = (const float*)d_in[5];
    const float* b2 = (const float*)d_in[6];

    const int IN = 256;
    const int n = in_sizes[0] / IN;
    const int E = in_sizes[2];
    const int* src = ei;
    const int* dst = ei + E;

    char* wsb = (char*)d_ws;
    size_t off = 0;
    auto alloc = [&](size_t bytes) -> void* {
        void* p = wsb + off;
        off = (off + bytes + 255) & ~(size_t)255;
        return p;
    };
    float* deg       = (float*)alloc((size_t)n * 4);        // becomes dinv
    int*   count     = (int*)alloc((size_t)n * 4);
    int*   row_start = (int*)alloc((size_t)(n + 1) * 4);
    int*   cursor    = (int*)alloc((size_t)n * 4);
    int*   partials  = (int*)alloc(4096);
    int*   csr_src   = (int*)alloc((size_t)E * 4);
    float* csr_norm  = (float*)alloc((size_t)E * 4);
    float* h         = (float*)alloc((size_t)n * HID * 4);  // GEMM output (both layers)
    float* out = (float*)d_out;
    float* act1 = out;  // layer-1 activations live in d_out (no aliasing hazard)

    const int nscan = (n + 1023) / 1024;

    hipLaunchKernelGGL(init_deg_kernel, dim3((n + 255) / 256), dim3(256), 0, stream,
                       deg, count, n);
    hipLaunchKernelGGL(count_deg_kernel, dim3((E + 255) / 256), dim3(256), 0, stream,
                       dst, ew, deg, count, E);
    hipLaunchKernelGGL(scan1_kernel, dim3(nscan), dim3(1024), 0, stream,
                       count, row_start, partials, n);
    hipLaunchKernelGGL(scan2_kernel, dim3(1), dim3(1024), 0, stream, partials, nscan);
    hipLaunchKernelGGL(finalize_kernel, dim3((n + 255) / 256), dim3(256), 0, stream,
                       partials, row_start, deg, cursor, n, E);
    hipLaunchKernelGGL(fill_csr_kernel, dim3((E + 255) / 256), dim3(256), 0, stream,
                       src, dst, ew, row_start, cursor, deg, csr_src, csr_norm, E);

    // layer 1: gemm -> h ; aggregate(h) -> act1 (= d_out)
    hipLaunchKernelGGL((gemm_kernel<256>), dim3((n + 63) / 64), dim3(256), 0, stream,
                       x, W1, h, n);
    hipLaunchKernelGGL(aggregate_gelu_kernel, dim3((n + 1) / 2), dim3(256), 0, stream,
                       h, row_start, csr_src, csr_norm, deg, b1, act1, n);
    // layer 2: gemm(act1) -> h ; aggregate(h) -> d_out
    hipLaunchKernelGGL((gemm_kernel<128>), dim3((n + 63) / 64), dim3(256), 0, stream,
                       act1, W2, h, n);
    hipLaunchKernelGGL(aggregate_gelu_kernel, dim3((n + 1) / 2), dim3(256), 0, stream,
                       h, row_start, csr_src, csr_norm, deg, b2, out, n);
}

// Round 4
// 709.472 us; speedup vs baseline: 1.5664x; 1.5664x over previous
//
#include <hip/hip_runtime.h>
#include <math.h>

// ---------------------------------------------------------------------------
// GCN 2-layer: per layer  out = Ahat @ (x @ W) + b, then erf-GELU.
// CSR built on device each call; dinv shared across layers.
// This round: h (GEMM output, gather source) stored as bf16 -> 256 B/row
// gathers, 25.6 MB footprint (cache-resident), wave-per-node aggregate with
// 4-edge unroll. Accumulation and act1 stay fp32.
// ---------------------------------------------------------------------------

#define HID 128

__device__ __forceinline__ unsigned short f2bf(float f) {
    unsigned int u = __float_as_uint(f);
    u = (u + 0x7fff + ((u >> 16) & 1)) >> 16;   // round-to-nearest-even
    return (unsigned short)u;
}
__device__ __forceinline__ float bfu2f(unsigned int lo16) {  // low 16 bits = bf16
    return __uint_as_float(lo16 << 16);
}

__global__ __launch_bounds__(256) void init_deg_kernel(float* deg, int* count, int n) {
    int i = blockIdx.x * 256 + threadIdx.x;
    if (i < n) { deg[i] = 1.0f; count[i] = 0; }
}

__global__ __launch_bounds__(256) void count_deg_kernel(const int* __restrict__ dst,
                                                        const float* __restrict__ w,
                                                        float* __restrict__ deg,
                                                        int* __restrict__ count, int E) {
    int e = blockIdx.x * 256 + threadIdx.x;
    if (e < E) {
        int d = dst[e];
        atomicAdd(&deg[d], w[e]);
        atomicAdd(&count[d], 1);
    }
}

__global__ __launch_bounds__(1024) void scan1_kernel(const int* __restrict__ count,
                                                     int* __restrict__ row_start,
                                                     int* __restrict__ partials, int n) {
    __shared__ int sdata[1024];
    int t = threadIdx.x;
    int gid = blockIdx.x * 1024 + t;
    int v = (gid < n) ? count[gid] : 0;
    sdata[t] = v;
    __syncthreads();
    for (int off = 1; off < 1024; off <<= 1) {
        int x = (t >= off) ? sdata[t - off] : 0;
        __syncthreads();
        sdata[t] += x;
        __syncthreads();
    }
    if (gid < n) row_start[gid] = sdata[t] - v;  // exclusive
    if (t == 1023) partials[blockIdx.x] = sdata[t];
}

__global__ __launch_bounds__(1024) void scan2_kernel(int* partials, int nparts) {
    __shared__ int sdata[1024];
    int t = threadIdx.x;
    int v = (t < nparts) ? partials[t] : 0;
    sdata[t] = v;
    __syncthreads();
    for (int off = 1; off < 1024; off <<= 1) {
        int x = (t >= off) ? sdata[t - off] : 0;
        __syncthreads();
        sdata[t] += x;
        __syncthreads();
    }
    if (t < nparts) partials[t] = sdata[t] - v;  // exclusive
}

__global__ __launch_bounds__(256) void finalize_kernel(const int* __restrict__ partials,
                                                       int* __restrict__ row_start,
                                                       float* __restrict__ deg,  // -> dinv
                                                       int* __restrict__ cursor, int n, int E) {
    int i = blockIdx.x * 256 + threadIdx.x;
    if (i < n) {
        row_start[i] += partials[i >> 10];
        cursor[i] = 0;
        deg[i] = rsqrtf(deg[i]);  // deg >= 1 (self loop)
    }
    if (i == 0) row_start[n] = E;
}

__global__ __launch_bounds__(256) void fill_csr_kernel(const int* __restrict__ src,
                                                       const int* __restrict__ dst,
                                                       const float* __restrict__ w,
                                                       const int* __restrict__ row_start,
                                                       int* __restrict__ cursor,
                                                       const float* __restrict__ dinv,
                                                       int* __restrict__ csr_src,
                                                       float* __restrict__ csr_norm, int E) {
    int e = blockIdx.x * 256 + threadIdx.x;
    if (e >= E) return;
    int s = src[e], d = dst[e];
    float nw = dinv[s] * w[e] * dinv[d];
    int pos = row_start[d] + atomicAdd(&cursor[d], 1);
    csr_src[pos] = s;
    csr_norm[pos] = nw;
}

// ---------------------------------------------------------------------------
// GEMM: H_bf16[n][128] = A[n][K] @ W[K][128]. fp32 compute, bf16 store.
// Tile 64 rows x 128 cols, K-chunk 32. acc[8][4] per thread.
// ---------------------------------------------------------------------------
template <int K>
__global__ __launch_bounds__(256) void gemm_kernel(const float* __restrict__ A,
                                                   const float* __restrict__ W,
                                                   unsigned int* __restrict__ Hb,  // bf16 pairs
                                                   int n) {
    __shared__ float xs[64][36];
    __shared__ float ws[32][128];
    const int t = threadIdx.x;
    const int block_row = blockIdx.x * 64;
    const int tc = t & 31;   // cols 4*tc .. 4*tc+3
    const int tr = t >> 5;   // rows tr, tr+8, ..., tr+56

    float acc[8][4];
#pragma unroll
    for (int i = 0; i < 8; i++)
#pragma unroll
        for (int j = 0; j < 4; j++) acc[i][j] = 0.f;

    for (int k0 = 0; k0 < K; k0 += 32) {
#pragma unroll
        for (int i = 0; i < 2; i++) {
            int idx = i * 256 + t;
            int r = idx >> 3;
            int c4 = idx & 7;
            float4 v = make_float4(0.f, 0.f, 0.f, 0.f);
            int gr = block_row + r;
            if (gr < n) v = *reinterpret_cast<const float4*>(&A[(size_t)gr * K + k0 + c4 * 4]);
            *reinterpret_cast<float4*>(&xs[r][c4 * 4]) = v;
        }
#pragma unroll
        for (int i = 0; i < 4; i++) {
            int idx = i * 256 + t;
            int r = idx >> 5;
            int c4 = idx & 31;
            float4 v = *reinterpret_cast<const float4*>(&W[(size_t)(k0 + r) * 128 + c4 * 4]);
            *reinterpret_cast<float4*>(&ws[r][c4 * 4]) = v;
        }
        __syncthreads();
#pragma unroll
        for (int kk = 0; kk < 32; kk++) {
            float wv[4];
            *reinterpret_cast<float4*>(wv) = *reinterpret_cast<const float4*>(&ws[kk][tc * 4]);
#pragma unroll
            for (int i = 0; i < 8; i++) {
                float xv = xs[tr + i * 8][kk];
                acc[i][0] += xv * wv[0];
                acc[i][1] += xv * wv[1];
                acc[i][2] += xv * wv[2];
                acc[i][3] += xv * wv[3];
            }
        }
        __syncthreads();
    }
#pragma unroll
    for (int i = 0; i < 8; i++) {
        int gr = block_row + tr + i * 8;
        if (gr < n) {
            uint2 p;
            p.x = (unsigned int)f2bf(acc[i][0]) | ((unsigned int)f2bf(acc[i][1]) << 16);
            p.y = (unsigned int)f2bf(acc[i][2]) | ((unsigned int)f2bf(acc[i][3]) << 16);
            *reinterpret_cast<uint2*>(&Hb[(size_t)gr * 64 + tc * 2]) = p;
        }
    }
}

// ---------------------------------------------------------------------------
// Aggregate + bias + erf-GELU. One WAVE (64 lanes) per node; lane c2 owns
// dims {2*c2, 2*c2+1} via packed 2xbf16 uint gathers. 4 nodes / 256-block.
// out[v][:] = gelu( b + dinv[v]^2 * h[v] + sum_e norm_e * h[src_e] )
// ---------------------------------------------------------------------------
__global__ __launch_bounds__(256) void aggregate_gelu_kernel(
        const unsigned int* __restrict__ hb,   // bf16 pairs, [n][64]
        const int* __restrict__ row_start,
        const int* __restrict__ csr_src,
        const float* __restrict__ csr_norm,
        const float* __restrict__ dinv,
        const float* __restrict__ bias,
        float* __restrict__ out, int n) {
    int node = blockIdx.x * 4 + (threadIdx.x >> 6);
    int c2 = threadIdx.x & 63;
    if (node >= n) return;

    float di = dinv[node];
    float dd = di * di;
    float2 b2 = *reinterpret_cast<const float2*>(&bias[c2 * 2]);
    unsigned int self = hb[(size_t)node * 64 + c2];
    float acc0 = b2.x + dd * bfu2f(self & 0xffffu);
    float acc1 = b2.y + dd * bfu2f(self >> 16);

    int e = row_start[node];
    const int e1 = row_start[node + 1];

    for (; e + 4 <= e1; e += 4) {
        int s0 = csr_src[e], s1 = csr_src[e + 1], s2 = csr_src[e + 2], s3 = csr_src[e + 3];
        float w0 = csr_norm[e], w1 = csr_norm[e + 1], w2 = csr_norm[e + 2], w3 = csr_norm[e + 3];
        unsigned int v0 = hb[(size_t)s0 * 64 + c2];
        unsigned int v1 = hb[(size_t)s1 * 64 + c2];
        unsigned int v2 = hb[(size_t)s2 * 64 + c2];
        unsigned int v3 = hb[(size_t)s3 * 64 + c2];
        acc0 += w0 * bfu2f(v0 & 0xffffu);  acc1 += w0 * bfu2f(v0 >> 16);
        acc0 += w1 * bfu2f(v1 & 0xffffu);  acc1 += w1 * bfu2f(v1 >> 16);
        acc0 += w2 * bfu2f(v2 & 0xffffu);  acc1 += w2 * bfu2f(v2 >> 16);
        acc0 += w3 * bfu2f(v3 & 0xffffu);  acc1 += w3 * bfu2f(v3 >> 16);
    }
    for (; e < e1; e++) {
        int s = csr_src[e];
        float w = csr_norm[e];
        unsigned int v = hb[(size_t)s * 64 + c2];
        acc0 += w * bfu2f(v & 0xffffu);
        acc1 += w * bfu2f(v >> 16);
    }

    float g0 = 0.5f * acc0 * (1.0f + erff(acc0 * 0.70710678118654752f));
    float g1 = 0.5f * acc1 * (1.0f + erff(acc1 * 0.70710678118654752f));
    *reinterpret_cast<float2*>(&out[(size_t)node * 128 + c2 * 2]) = make_float2(g0, g1);
}

// ---------------------------------------------------------------------------

extern "C" void kernel_launch(void* const* d_in, const int* in_sizes, int n_in,
                              void* d_out, int out_size, void* d_ws, size_t ws_size,
                              hipStream_t stream) {
    const float* x  = (const float*)d_in[0];
    const int*   ei = (const int*)d_in[1];
    const float* ew = (const float*)d_in[2];
    const float* W1 = (const float*)d_in[3];
    const float* b1 = (const float*)d_in[4];
    const float* W2 = (const float*)d_in[5];
    const float* b2 = (const float*)d_in[6];

    const int IN = 256;
    const int n = in_sizes[0] / IN;
    const int E = in_sizes[2];
    const int* src = ei;
    const int* dst = ei + E;

    char* wsb = (char*)d_ws;
    size_t off = 0;
    auto alloc = [&](size_t bytes) -> void* {
        void* p = wsb + off;
        off = (off + bytes + 255) & ~(size_t)255;
        return p;
    };
    float* deg       = (float*)alloc((size_t)n * 4);        // becomes dinv
    int*   count     = (int*)alloc((size_t)n * 4);
    int*   row_start = (int*)alloc((size_t)(n + 1) * 4);
    int*   cursor    = (int*)alloc((size_t)n * 4);
    int*   partials  = (int*)alloc(4096);
    int*   csr_src   = (int*)alloc((size_t)E * 4);
    float* csr_norm  = (float*)alloc((size_t)E * 4);
    unsigned int* hb = (unsigned int*)alloc((size_t)n * 64 * 4);  // bf16 h, 25.6 MB
    float* out = (float*)d_out;
    float* act1 = out;  // layer-1 activations live in d_out

    const int nscan = (n + 1023) / 1024;

    hipLaunchKernelGGL(init_deg_kernel, dim3((n + 255) / 256), dim3(256), 0, stream,
                       deg, count, n);
    hipLaunchKernelGGL(count_deg_kernel, dim3((E + 255) / 256), dim3(256), 0, stream,
                       dst, ew, deg, count, E);
    hipLaunchKernelGGL(scan1_kernel, dim3(nscan), dim3(1024), 0, stream,
                       count, row_start, partials, n);
    hipLaunchKernelGGL(scan2_kernel, dim3(1), dim3(1024), 0, stream, partials, nscan);
    hipLaunchKernelGGL(finalize_kernel, dim3((n + 255) / 256), dim3(256), 0, stream,
                       partials, row_start, deg, cursor, n, E);
    hipLaunchKernelGGL(fill_csr_kernel, dim3((E + 255) / 256), dim3(256), 0, stream,
                       src, dst, ew, row_start, cursor, deg, csr_src, csr_norm, E);

    // layer 1: gemm -> hb(bf16) ; aggregate(hb) -> act1 (= d_out, fp32)
    hipLaunchKernelGGL((gemm_kernel<256>), dim3((n + 63) / 64), dim3(256), 0, stream,
                       x, W1, hb, n);
    hipLaunchKernelGGL(aggregate_gelu_kernel, dim3((n + 3) / 4), dim3(256), 0, stream,
                       hb, row_start, csr_src, csr_norm, deg, b1, act1, n);
    // layer 2: gemm(act1) -> hb ; aggregate(hb) -> d_out
    hipLaunchKernelGGL((gemm_kernel<128>), dim3((n + 63) / 64), dim3(256), 0, stream,
                       act1, W2, hb, n);
    hipLaunchKernelGGL(aggregate_gelu_kernel, dim3((n + 3) / 4), dim3(256), 0, stream,
                       hb, row_start, csr_src, csr_norm, deg, b2, out, n);
}

// Round 5
// 629.882 us; speedup vs baseline: 1.7644x; 1.1264x over previous
//
#include <hip/hip_runtime.h>
#include <math.h>

// ---------------------------------------------------------------------------
// GCN 2-layer: per layer  out = Ahat @ (x @ W) + b, then erf-GELU.
// CSR built on device each call (counting sort, int atomics only).
// deg/dinv computed from CSR rows (no float atomics). Normalization folded
// into the aggregate via wave-uniform dinv[s] gathers. h stored bf16.
// ---------------------------------------------------------------------------

#define HID 128

__device__ __forceinline__ unsigned short f2bf(float f) {
    unsigned int u = __float_as_uint(f);
    u = (u + 0x7fff + ((u >> 16) & 1)) >> 16;   // round-to-nearest-even
    return (unsigned short)u;
}
__device__ __forceinline__ float bfu2f(unsigned int lo16) {  // low 16 bits = bf16
    return __uint_as_float(lo16 << 16);
}

__global__ __launch_bounds__(256) void init_kernel(int* count, int* cursor, int n) {
    int i = blockIdx.x * 256 + threadIdx.x;
    if (i < n) { count[i] = 0; cursor[i] = 0; }
}

__global__ __launch_bounds__(256) void count_kernel(const int* __restrict__ dst,
                                                    int* __restrict__ count, int E) {
    int e = blockIdx.x * 256 + threadIdx.x;
    if (e < E) atomicAdd(&count[dst[e]], 1);
}

// Hillis-Steele exclusive scan, 1024/block.
__global__ __launch_bounds__(1024) void scan1_kernel(const int* __restrict__ count,
                                                     int* __restrict__ row_start,
                                                     int* __restrict__ partials, int n) {
    __shared__ int sdata[1024];
    int t = threadIdx.x;
    int gid = blockIdx.x * 1024 + t;
    int v = (gid < n) ? count[gid] : 0;
    sdata[t] = v;
    __syncthreads();
    for (int off = 1; off < 1024; off <<= 1) {
        int x = (t >= off) ? sdata[t - off] : 0;
        __syncthreads();
        sdata[t] += x;
        __syncthreads();
    }
    if (gid < n) row_start[gid] = sdata[t] - v;  // exclusive
    if (t == 1023) partials[blockIdx.x] = sdata[t];
}

__global__ __launch_bounds__(1024) void scan2_kernel(int* partials, int nparts) {
    __shared__ int sdata[1024];
    int t = threadIdx.x;
    int v = (t < nparts) ? partials[t] : 0;
    sdata[t] = v;
    __syncthreads();
    for (int off = 1; off < 1024; off <<= 1) {
        int x = (t >= off) ? sdata[t - off] : 0;
        __syncthreads();
        sdata[t] += x;
        __syncthreads();
    }
    if (t < nparts) partials[t] = sdata[t] - v;  // exclusive
}

__global__ __launch_bounds__(256) void finalize_kernel(const int* __restrict__ partials,
                                                       int* __restrict__ row_start,
                                                       int n, int E) {
    int i = blockIdx.x * 256 + threadIdx.x;
    if (i < n) row_start[i] += partials[i >> 10];
    if (i == 0) row_start[n] = E;
}

// Scatter (src, raw weight) into CSR position. Order within a row arbitrary.
__global__ __launch_bounds__(256) void fill_kernel(const int* __restrict__ src,
                                                   const int* __restrict__ dst,
                                                   const float* __restrict__ w,
                                                   const int* __restrict__ row_start,
                                                   int* __restrict__ cursor,
                                                   uint2* __restrict__ csr_sw, int E) {
    int e = blockIdx.x * 256 + threadIdx.x;
    if (e >= E) return;
    int s = src[e], d = dst[e];
    int pos = row_start[d] + atomicAdd(&cursor[d], 1);
    csr_sw[pos] = make_uint2((unsigned int)s, __float_as_uint(w[e]));
}

// deg[i] = 1 + sum of row weights; dinv = rsqrt(deg). Thread per node.
__global__ __launch_bounds__(256) void dinv_kernel(const uint2* __restrict__ csr_sw,
                                                   const int* __restrict__ row_start,
                                                   float* __restrict__ dinv, int n) {
    int i = blockIdx.x * 256 + threadIdx.x;
    if (i >= n) return;
    float dsum = 1.0f;
    int e1 = row_start[i + 1];
    for (int e = row_start[i]; e < e1; e++) dsum += __uint_as_float(csr_sw[e].y);
    dinv[i] = rsqrtf(dsum);
}

// ---------------------------------------------------------------------------
// GEMM: H_bf16[n][128] = A[n][K] @ W[K][128]. fp32 compute, bf16 store.
// ---------------------------------------------------------------------------
template <int K>
__global__ __launch_bounds__(256) void gemm_kernel(const float* __restrict__ A,
                                                   const float* __restrict__ W,
                                                   unsigned int* __restrict__ Hb,  // bf16 pairs
                                                   int n) {
    __shared__ float xs[64][36];
    __shared__ float ws[32][128];
    const int t = threadIdx.x;
    const int block_row = blockIdx.x * 64;
    const int tc = t & 31;
    const int tr = t >> 5;

    float acc[8][4];
#pragma unroll
    for (int i = 0; i < 8; i++)
#pragma unroll
        for (int j = 0; j < 4; j++) acc[i][j] = 0.f;

    for (int k0 = 0; k0 < K; k0 += 32) {
#pragma unroll
        for (int i = 0; i < 2; i++) {
            int idx = i * 256 + t;
            int r = idx >> 3;
            int c4 = idx & 7;
            float4 v = make_float4(0.f, 0.f, 0.f, 0.f);
            int gr = block_row + r;
            if (gr < n) v = *reinterpret_cast<const float4*>(&A[(size_t)gr * K + k0 + c4 * 4]);
            *reinterpret_cast<float4*>(&xs[r][c4 * 4]) = v;
        }
#pragma unroll
        for (int i = 0; i < 4; i++) {
            int idx = i * 256 + t;
            int r = idx >> 5;
            int c4 = idx & 31;
            float4 v = *reinterpret_cast<const float4*>(&W[(size_t)(k0 + r) * 128 + c4 * 4]);
            *reinterpret_cast<float4*>(&ws[r][c4 * 4]) = v;
        }
        __syncthreads();
#pragma unroll
        for (int kk = 0; kk < 32; kk++) {
            float wv[4];
            *reinterpret_cast<float4*>(wv) = *reinterpret_cast<const float4*>(&ws[kk][tc * 4]);
#pragma unroll
            for (int i = 0; i < 8; i++) {
                float xv = xs[tr + i * 8][kk];
                acc[i][0] += xv * wv[0];
                acc[i][1] += xv * wv[1];
                acc[i][2] += xv * wv[2];
                acc[i][3] += xv * wv[3];
            }
        }
        __syncthreads();
    }
#pragma unroll
    for (int i = 0; i < 8; i++) {
        int gr = block_row + tr + i * 8;
        if (gr < n) {
            uint2 p;
            p.x = (unsigned int)f2bf(acc[i][0]) | ((unsigned int)f2bf(acc[i][1]) << 16);
            p.y = (unsigned int)f2bf(acc[i][2]) | ((unsigned int)f2bf(acc[i][3]) << 16);
            *reinterpret_cast<uint2*>(&Hb[(size_t)gr * 64 + tc * 2]) = p;
        }
    }
}

// ---------------------------------------------------------------------------
// Aggregate + bias + erf-GELU. One wave per node; lane c2 owns dims
// {2*c2, 2*c2+1}. Normalization folded in:
//   out[v] = gelu( b + dinv[v]^2 * h[v] + dinv[v] * sum_e w_e*dinv[s_e]*h[s_e] )
// csr_sw[e] and dinv[s] loads are wave-uniform (broadcast).
// ---------------------------------------------------------------------------
__global__ __launch_bounds__(256) void aggregate_gelu_kernel(
        const unsigned int* __restrict__ hb,   // bf16 pairs, [n][64]
        const int* __restrict__ row_start,
        const uint2* __restrict__ csr_sw,
        const float* __restrict__ dinv,
        const float* __restrict__ bias,
        float* __restrict__ out, int n) {
    int node = blockIdx.x * 4 + (threadIdx.x >> 6);
    int c2 = threadIdx.x & 63;
    if (node >= n) return;

    float di = dinv[node];
    float dd = di * di;
    float2 b2 = *reinterpret_cast<const float2*>(&bias[c2 * 2]);
    unsigned int self = hb[(size_t)node * 64 + c2];
    float s0 = 0.f, s1 = 0.f;   // edge accumulators (pre dinv[v] scale)

    int e = row_start[node];
    const int e1 = row_start[node + 1];

    for (; e + 4 <= e1; e += 4) {
        uint2 ew0 = csr_sw[e],     ew1 = csr_sw[e + 1];
        uint2 ew2 = csr_sw[e + 2], ew3 = csr_sw[e + 3];
        float m0 = __uint_as_float(ew0.y) * dinv[ew0.x];
        float m1 = __uint_as_float(ew1.y) * dinv[ew1.x];
        float m2 = __uint_as_float(ew2.y) * dinv[ew2.x];
        float m3 = __uint_as_float(ew3.y) * dinv[ew3.x];
        unsigned int v0 = hb[(size_t)ew0.x * 64 + c2];
        unsigned int v1 = hb[(size_t)ew1.x * 64 + c2];
        unsigned int v2 = hb[(size_t)ew2.x * 64 + c2];
        unsigned int v3 = hb[(size_t)ew3.x * 64 + c2];
        s0 += m0 * bfu2f(v0 & 0xffffu);  s1 += m0 * bfu2f(v0 >> 16);
        s0 += m1 * bfu2f(v1 & 0xffffu);  s1 += m1 * bfu2f(v1 >> 16);
        s0 += m2 * bfu2f(v2 & 0xffffu);  s1 += m2 * bfu2f(v2 >> 16);
        s0 += m3 * bfu2f(v3 & 0xffffu);  s1 += m3 * bfu2f(v3 >> 16);
    }
    for (; e < e1; e++) {
        uint2 ew = csr_sw[e];
        float m = __uint_as_float(ew.y) * dinv[ew.x];
        unsigned int v = hb[(size_t)ew.x * 64 + c2];
        s0 += m * bfu2f(v & 0xffffu);
        s1 += m * bfu2f(v >> 16);
    }

    float acc0 = b2.x + dd * bfu2f(self & 0xffffu) + di * s0;
    float acc1 = b2.y + dd * bfu2f(self >> 16) + di * s1;
    float g0 = 0.5f * acc0 * (1.0f + erff(acc0 * 0.70710678118654752f));
    float g1 = 0.5f * acc1 * (1.0f + erff(acc1 * 0.70710678118654752f));
    *reinterpret_cast<float2*>(&out[(size_t)node * 128 + c2 * 2]) = make_float2(g0, g1);
}

// ---------------------------------------------------------------------------

extern "C" void kernel_launch(void* const* d_in, const int* in_sizes, int n_in,
                              void* d_out, int out_size, void* d_ws, size_t ws_size,
                              hipStream_t stream) {
    const float* x  = (const float*)d_in[0];
    const int*   ei = (const int*)d_in[1];
    const float* ew = (const float*)d_in[2];
    const float* W1 = (const float*)d_in[3];
    const float* b1 = (const float*)d_in[4];
    const float* W2 = (const float*)d_in[5];
    const float* b2 = (const float*)d_in[6];

    const int IN = 256;
    const int n = in_sizes[0] / IN;
    const int E = in_sizes[2];
    const int* src = ei;
    const int* dst = ei + E;

    char* wsb = (char*)d_ws;
    size_t off = 0;
    auto alloc = [&](size_t bytes) -> void* {
        void* p = wsb + off;
        off = (off + bytes + 255) & ~(size_t)255;
        return p;
    };
    int*   count     = (int*)alloc((size_t)n * 4);
    int*   cursor    = (int*)alloc((size_t)n * 4);
    int*   row_start = (int*)alloc((size_t)(n + 1) * 4);
    int*   partials  = (int*)alloc(4096);
    float* dinv      = (float*)alloc((size_t)n * 4);
    uint2* csr_sw    = (uint2*)alloc((size_t)E * 8);
    unsigned int* hb = (unsigned int*)alloc((size_t)n * 64 * 4);  // bf16 h
    float* out = (float*)d_out;
    float* act1 = out;  // layer-1 activations live in d_out

    const int nscan = (n + 1023) / 1024;

    hipLaunchKernelGGL(init_kernel, dim3((n + 255) / 256), dim3(256), 0, stream,
                       count, cursor, n);
    hipLaunchKernelGGL(count_kernel, dim3((E + 255) / 256), dim3(256), 0, stream,
                       dst, count, E);
    hipLaunchKernelGGL(scan1_kernel, dim3(nscan), dim3(1024), 0, stream,
                       count, row_start, partials, n);
    hipLaunchKernelGGL(scan2_kernel, dim3(1), dim3(1024), 0, stream, partials, nscan);
    hipLaunchKernelGGL(finalize_kernel, dim3((n + 255) / 256), dim3(256), 0, stream,
                       partials, row_start, n, E);
    hipLaunchKernelGGL(fill_kernel, dim3((E + 255) / 256), dim3(256), 0, stream,
                       src, dst, ew, row_start, cursor, csr_sw, E);
    hipLaunchKernelGGL(dinv_kernel, dim3((n + 255) / 256), dim3(256), 0, stream,
                       csr_sw, row_start, dinv, n);

    // layer 1: gemm -> hb(bf16) ; aggregate(hb) -> act1 (= d_out, fp32)
    hipLaunchKernelGGL((gemm_kernel<256>), dim3((n + 63) / 64), dim3(256), 0, stream,
                       x, W1, hb, n);
    hipLaunchKernelGGL(aggregate_gelu_kernel, dim3((n + 3) / 4), dim3(256), 0, stream,
                       hb, row_start, csr_sw, dinv, b1, act1, n);
    // layer 2: gemm(act1) -> hb ; aggregate(hb) -> d_out
    hipLaunchKernelGGL((gemm_kernel<128>), dim3((n + 63) / 64), dim3(256), 0, stream,
                       act1, W2, hb, n);
    hipLaunchKernelGGL(aggregate_gelu_kernel, dim3((n + 3) / 4), dim3(256), 0, stream,
                       hb, row_start, csr_sw, dinv, b2, out, n);
}

// Round 7
// 496.245 us; speedup vs baseline: 2.2395x; 1.2693x over previous
//
#include <hip/hip_runtime.h>
#include <math.h>

// ---------------------------------------------------------------------------
// GCN 2-layer: per layer  out = Ahat @ (x @ W) + b, then erf-GELU.
// This round: bf16 MFMA GEMMs (fp32 accum), atomic-free CSR fill (lpos saved
// from count pass), act1 stored bf16. xb/act1b staged inside d_out.
// ---------------------------------------------------------------------------

#define HID 128

typedef __attribute__((ext_vector_type(8))) short bf16x8;
typedef __attribute__((ext_vector_type(4))) float f32x4;

__device__ __forceinline__ unsigned short f2bf(float f) {
    unsigned int u = __float_as_uint(f);
    u = (u + 0x7fff + ((u >> 16) & 1)) >> 16;   // round-to-nearest-even
    return (unsigned short)u;
}
__device__ __forceinline__ float bfu2f(unsigned int lo16) {  // low 16 bits = bf16
    return __uint_as_float(lo16 << 16);
}

// ---- conversions ----------------------------------------------------------

// fp32 -> bf16, 8 elems/thread. total must be multiple of 8 (n*256 is).
__global__ __launch_bounds__(256) void cvt_x_kernel(const float* __restrict__ in,
                                                    unsigned int* __restrict__ outb,
                                                    long total8) {
    long g = (long)blockIdx.x * 256 + threadIdx.x;
    if (g >= total8) return;
    const float4* p = reinterpret_cast<const float4*>(in + g * 8);
    float4 a = p[0], b = p[1];
    uint4 o;
    o.x = (unsigned int)f2bf(a.x) | ((unsigned int)f2bf(a.y) << 16);
    o.y = (unsigned int)f2bf(a.z) | ((unsigned int)f2bf(a.w) << 16);
    o.z = (unsigned int)f2bf(b.x) | ((unsigned int)f2bf(b.y) << 16);
    o.w = (unsigned int)f2bf(b.z) | ((unsigned int)f2bf(b.w) << 16);
    *reinterpret_cast<uint4*>(outb + g * 4) = o;
}

// W[k][128] fp32 -> Wt[128][K] bf16 for both layers in one launch.
__global__ __launch_bounds__(256) void cvt_wt_kernel(const float* __restrict__ W1,
                                                     unsigned short* __restrict__ Wt1, int K1,
                                                     const float* __restrict__ W2,
                                                     unsigned short* __restrict__ Wt2, int K2) {
    int t = blockIdx.x * 256 + threadIdx.x;
    int n1 = 128 * K1;
    if (t < n1) {
        int k = t % K1, c = t / K1;
        Wt1[c * K1 + k] = f2bf(W1[(size_t)k * 128 + c]);
        return;
    }
    t -= n1;
    if (t < 128 * K2) {
        int k = t % K2, c = t / K2;
        Wt2[c * K2 + k] = f2bf(W2[(size_t)k * 128 + c]);
    }
}

// ---- CSR build ------------------------------------------------------------

__global__ __launch_bounds__(256) void init_kernel(int* count, int n) {
    int i = blockIdx.x * 256 + threadIdx.x;
    if (i < n) count[i] = 0;
}

__global__ __launch_bounds__(256) void count_kernel(const int* __restrict__ dst,
                                                    int* __restrict__ count,
                                                    int* __restrict__ lpos, int E) {
    int e = blockIdx.x * 256 + threadIdx.x;
    if (e < E) lpos[e] = atomicAdd(&count[dst[e]], 1);
}

__global__ __launch_bounds__(1024) void scan1_kernel(const int* __restrict__ count,
                                                     int* __restrict__ row_start,
                                                     int* __restrict__ partials, int n) {
    __shared__ int sdata[1024];
    int t = threadIdx.x;
    int gid = blockIdx.x * 1024 + t;
    int v = (gid < n) ? count[gid] : 0;
    sdata[t] = v;
    __syncthreads();
    for (int off = 1; off < 1024; off <<= 1) {
        int x = (t >= off) ? sdata[t - off] : 0;
        __syncthreads();
        sdata[t] += x;
        __syncthreads();
    }
    if (gid < n) row_start[gid] = sdata[t] - v;  // exclusive
    if (t == 1023) partials[blockIdx.x] = sdata[t];
}

__global__ __launch_bounds__(1024) void scan2_kernel(int* partials, int nparts) {
    __shared__ int sdata[1024];
    int t = threadIdx.x;
    int v = (t < nparts) ? partials[t] : 0;
    sdata[t] = v;
    __syncthreads();
    for (int off = 1; off < 1024; off <<= 1) {
        int x = (t >= off) ? sdata[t - off] : 0;
        __syncthreads();
        sdata[t] += x;
        __syncthreads();
    }
    if (t < nparts) partials[t] = sdata[t] - v;  // exclusive
}

__global__ __launch_bounds__(256) void finalize_kernel(const int* __restrict__ partials,
                                                       int* __restrict__ row_start,
                                                       int n, int E) {
    int i = blockIdx.x * 256 + threadIdx.x;
    if (i < n) row_start[i] += partials[i >> 10];
    if (i == 0) row_start[n] = E;
}

// Atomic-free scatter using saved local positions.
__global__ __launch_bounds__(256) void fill_kernel(const int* __restrict__ src,
                                                   const int* __restrict__ dst,
                                                   const float* __restrict__ w,
                                                   const int* __restrict__ row_start,
                                                   const int* __restrict__ lpos,
                                                   uint2* __restrict__ csr_sw, int E) {
    int e = blockIdx.x * 256 + threadIdx.x;
    if (e >= E) return;
    int d = dst[e];
    int pos = row_start[d] + lpos[e];
    csr_sw[pos] = make_uint2((unsigned int)src[e], __float_as_uint(w[e]));
}

__global__ __launch_bounds__(256) void dinv_kernel(const uint2* __restrict__ csr_sw,
                                                   const int* __restrict__ row_start,
                                                   float* __restrict__ dinv, int n) {
    int i = blockIdx.x * 256 + threadIdx.x;
    if (i >= n) return;
    float dsum = 1.0f;
    int e1 = row_start[i + 1];
    for (int e = row_start[i]; e < e1; e++) dsum += __uint_as_float(csr_sw[e].y);
    dinv[i] = rsqrtf(dsum);
}

// ---------------------------------------------------------------------------
// MFMA GEMM: Hb[n][128] = Ab[n][K] @ Wt^T, all bf16 in / fp32 accum / bf16 out.
// Tile 128x128, BK=32, 4 waves. Wave w: rows 32w..32w+31 (2 M-frags) x 8
// N-frags. Frag layout (16x16x32): A lane l holds row l&15, k=(l>>4)*8+i;
// B lane l holds col l&15, k=(l>>4)*8+i; C/D: col=lane&15, row=(lane>>4)*4+r.
// ---------------------------------------------------------------------------
template <int K>
__global__ __launch_bounds__(256) void gemm_mfma_kernel(
        const unsigned short* __restrict__ Ab,   // [n][K] bf16
        const unsigned short* __restrict__ Wt,   // [128][K] bf16 (transposed W)
        unsigned short* __restrict__ Hb,         // [n][128] bf16
        int n) {
    __shared__ unsigned short Asl[128][40];   // 32 bf16 + pad to 40 (80B rows)
    __shared__ unsigned short Btl[128][40];
    const int t = threadIdx.x;
    const int w = t >> 6;
    const int l = t & 63;
    const int lr = l & 15;
    const int ks = l >> 4;          // 0..3
    const int brow = blockIdx.x * 128;

    f32x4 acc[2][8];
#pragma unroll
    for (int m = 0; m < 2; m++)
#pragma unroll
        for (int j = 0; j < 8; j++) acc[m][j] = (f32x4)(0.f);

    for (int k0 = 0; k0 < K; k0 += 32) {
        // stage A: 128 rows x 32 bf16 (64B/row) = 512 x 16B, 2/thread
#pragma unroll
        for (int i = 0; i < 2; i++) {
            int idx = i * 256 + t;
            int r = idx >> 2;
            int c8 = idx & 3;
            int gr = brow + r;
            uint4 v = make_uint4(0u, 0u, 0u, 0u);
            if (gr < n) v = *reinterpret_cast<const uint4*>(&Ab[(size_t)gr * K + k0 + c8 * 8]);
            *reinterpret_cast<uint4*>(&Asl[r][c8 * 8]) = v;
        }
        // stage Bt: 128 cols x 32 k
#pragma unroll
        for (int i = 0; i < 2; i++) {
            int idx = i * 256 + t;
            int r = idx >> 2;
            int c8 = idx & 3;
            uint4 v = *reinterpret_cast<const uint4*>(&Wt[(size_t)r * K + k0 + c8 * 8]);
            *reinterpret_cast<uint4*>(&Btl[r][c8 * 8]) = v;
        }
        __syncthreads();

        bf16x8 af[2];
#pragma unroll
        for (int m = 0; m < 2; m++)
            af[m] = *reinterpret_cast<const bf16x8*>(&Asl[w * 32 + m * 16 + lr][ks * 8]);
#pragma unroll
        for (int j = 0; j < 8; j++) {
            bf16x8 bfr = *reinterpret_cast<const bf16x8*>(&Btl[j * 16 + lr][ks * 8]);
            acc[0][j] = __builtin_amdgcn_mfma_f32_16x16x32_bf16(af[0], bfr, acc[0][j], 0, 0, 0);
            acc[1][j] = __builtin_amdgcn_mfma_f32_16x16x32_bf16(af[1], bfr, acc[1][j], 0, 0, 0);
        }
        __syncthreads();
    }

#pragma unroll
    for (int m = 0; m < 2; m++) {
#pragma unroll
        for (int r = 0; r < 4; r++) {
            int row = brow + w * 32 + m * 16 + ks * 4 + r;
            if (row < n) {
#pragma unroll
                for (int j = 0; j < 8; j++)
                    Hb[(size_t)row * 128 + j * 16 + lr] = f2bf(acc[m][j][r]);
            }
        }
    }
}

// ---------------------------------------------------------------------------
// Aggregate + bias + erf-GELU. One wave per node; lane c2 owns dims
// {2*c2, 2*c2+1}. out = gelu(b + dinv^2*h_self + dinv * sum w_e*dinv[s]*h[s]).
// BF16_OUT: pack output as 2xbf16 uint (layer 1); else fp32 float2 (layer 2).
// ---------------------------------------------------------------------------
template <bool BF16_OUT>
__global__ __launch_bounds__(256) void aggregate_gelu_kernel(
        const unsigned int* __restrict__ hb,   // bf16 pairs, [n][64]
        const int* __restrict__ row_start,
        const uint2* __restrict__ csr_sw,
        const float* __restrict__ dinv,
        const float* __restrict__ bias,
        unsigned int* __restrict__ outb,
        float* __restrict__ outf, int n) {
    int node = blockIdx.x * 4 + (threadIdx.x >> 6);
    int c2 = threadIdx.x & 63;
    if (node >= n) return;

    float di = dinv[node];
    float dd = di * di;
    float2 b2 = *reinterpret_cast<const float2*>(&bias[c2 * 2]);
    unsigned int self = hb[(size_t)node * 64 + c2];
    float s0 = 0.f, s1 = 0.f;

    int e = row_start[node];
    const int e1 = row_start[node + 1];

    for (; e + 4 <= e1; e += 4) {
        uint2 ew0 = csr_sw[e],     ew1 = csr_sw[e + 1];
        uint2 ew2 = csr_sw[e + 2], ew3 = csr_sw[e + 3];
        float m0 = __uint_as_float(ew0.y) * dinv[ew0.x];
        float m1 = __uint_as_float(ew1.y) * dinv[ew1.x];
        float m2 = __uint_as_float(ew2.y) * dinv[ew2.x];
        float m3 = __uint_as_float(ew3.y) * dinv[ew3.x];
        unsigned int v0 = hb[(size_t)ew0.x * 64 + c2];
        unsigned int v1 = hb[(size_t)ew1.x * 64 + c2];
        unsigned int v2 = hb[(size_t)ew2.x * 64 + c2];
        unsigned int v3 = hb[(size_t)ew3.x * 64 + c2];
        s0 += m0 * bfu2f(v0 & 0xffffu);  s1 += m0 * bfu2f(v0 >> 16);
        s0 += m1 * bfu2f(v1 & 0xffffu);  s1 += m1 * bfu2f(v1 >> 16);
        s0 += m2 * bfu2f(v2 & 0xffffu);  s1 += m2 * bfu2f(v2 >> 16);
        s0 += m3 * bfu2f(v3 & 0xffffu);  s1 += m3 * bfu2f(v3 >> 16);
    }
    for (; e < e1; e++) {
        uint2 ew = csr_sw[e];
        float m = __uint_as_float(ew.y) * dinv[ew.x];
        unsigned int v = hb[(size_t)ew.x * 64 + c2];
        s0 += m * bfu2f(v & 0xffffu);
        s1 += m * bfu2f(v >> 16);
    }

    float acc0 = b2.x + dd * bfu2f(self & 0xffffu) + di * s0;
    float acc1 = b2.y + dd * bfu2f(self >> 16) + di * s1;
    float g0 = 0.5f * acc0 * (1.0f + erff(acc0 * 0.70710678118654752f));
    float g1 = 0.5f * acc1 * (1.0f + erff(acc1 * 0.70710678118654752f));
    if (BF16_OUT) {
        outb[(size_t)node * 64 + c2] =
            (unsigned int)f2bf(g0) | ((unsigned int)f2bf(g1) << 16);
    } else {
        *reinterpret_cast<float2*>(&outf[(size_t)node * 128 + c2 * 2]) = make_float2(g0, g1);
    }
}

// ---------------------------------------------------------------------------

extern "C" void kernel_launch(void* const* d_in, const int* in_sizes, int n_in,
                              void* d_out, int out_size, void* d_ws, size_t ws_size,
                              hipStream_t stream) {
    const float* x  = (const float*)d_in[0];
    const int*   ei = (const int*)d_in[1];
    const float* ew = (const float*)d_in[2];
    const float* W1 = (const float*)d_in[3];
    const float* b1 = (const float*)d_in[4];
    const float* W2 = (const float*)d_in[5];
    const float* b2 = (const float*)d_in[6];

    const int IN = 256;
    const int n = in_sizes[0] / IN;
    const int E = in_sizes[2];
    const int* src = ei;
    const int* dst = ei + E;

    char* wsb = (char*)d_ws;
    size_t off = 0;
    auto alloc = [&](size_t bytes) -> void* {
        void* p = wsb + off;
        off = (off + bytes + 255) & ~(size_t)255;
        return p;
    };
    int*   count     = (int*)alloc((size_t)n * 4);
    int*   lpos      = (int*)alloc((size_t)E * 4);
    int*   row_start = (int*)alloc((size_t)(n + 1) * 4);
    int*   partials  = (int*)alloc(4096);
    float* dinv      = (float*)alloc((size_t)n * 4);
    uint2* csr_sw    = (uint2*)alloc((size_t)E * 8);
    unsigned short* hb  = (unsigned short*)alloc((size_t)n * HID * 2);  // bf16 h
    unsigned short* wt1 = (unsigned short*)alloc((size_t)128 * IN * 2);
    unsigned short* wt2 = (unsigned short*)alloc((size_t)128 * HID * 2);

    // xb (bf16 x, 51.2 MB) and act1b (bf16 act1, 25.6 MB) live inside d_out:
    // xb dead after gemm1; act1b (at d_out base) dead after gemm2; final
    // aggregate overwrites d_out with fp32 output.
    unsigned short* xb    = (unsigned short*)d_out;
    unsigned short* act1b = (unsigned short*)d_out;
    float* out = (float*)d_out;

    const int nscan = (n + 1023) / 1024;

    // conversions
    long total8 = (long)n * IN / 8;
    hipLaunchKernelGGL(cvt_x_kernel, dim3((unsigned)((total8 + 255) / 256)), dim3(256), 0,
                       stream, x, (unsigned int*)xb, total8);
    int wtot = 128 * IN + 128 * HID;
    hipLaunchKernelGGL(cvt_wt_kernel, dim3((wtot + 255) / 256), dim3(256), 0, stream,
                       W1, wt1, IN, W2, wt2, HID);

    // CSR build
    hipLaunchKernelGGL(init_kernel, dim3((n + 255) / 256), dim3(256), 0, stream, count, n);
    hipLaunchKernelGGL(count_kernel, dim3((E + 255) / 256), dim3(256), 0, stream,
                       dst, count, lpos, E);
    hipLaunchKernelGGL(scan1_kernel, dim3(nscan), dim3(1024), 0, stream,
                       count, row_start, partials, n);
    hipLaunchKernelGGL(scan2_kernel, dim3(1), dim3(1024), 0, stream, partials, nscan);
    hipLaunchKernelGGL(finalize_kernel, dim3((n + 255) / 256), dim3(256), 0, stream,
                       partials, row_start, n, E);
    hipLaunchKernelGGL(fill_kernel, dim3((E + 255) / 256), dim3(256), 0, stream,
                       src, dst, ew, row_start, lpos, csr_sw, E);
    hipLaunchKernelGGL(dinv_kernel, dim3((n + 255) / 256), dim3(256), 0, stream,
                       csr_sw, row_start, dinv, n);

    // layer 1: mfma gemm (xb -> hb) ; aggregate -> act1b (bf16, in d_out)
    hipLaunchKernelGGL((gemm_mfma_kernel<256>), dim3((n + 127) / 128), dim3(256), 0, stream,
                       xb, wt1, hb, n);
    hipLaunchKernelGGL((aggregate_gelu_kernel<true>), dim3((n + 3) / 4), dim3(256), 0, stream,
                       (const unsigned int*)hb, row_start, csr_sw, dinv, b1,
                       (unsigned int*)act1b, nullptr, n);
    // layer 2: mfma gemm (act1b -> hb) ; aggregate -> out (fp32)
    hipLaunchKernelGGL((gemm_mfma_kernel<128>), dim3((n + 127) / 128), dim3(256), 0, stream,
                       act1b, wt2, hb, n);
    hipLaunchKernelGGL((aggregate_gelu_kernel<false>), dim3((n + 3) / 4), dim3(256), 0, stream,
                       (const unsigned int*)hb, row_start, csr_sw, dinv, b2,
                       nullptr, out, n);
}

// Round 8
// 472.642 us; speedup vs baseline: 2.3513x; 1.0499x over previous
//
#include <hip/hip_runtime.h>
#include <math.h>

// ---------------------------------------------------------------------------
// GCN 2-layer: per layer  out = Ahat @ (x @ W) + b, then erf-GELU.
// bf16 MFMA GEMMs (fp32 accum), atomic-free CSR fill, bf16 h/act1.
// This round: count||cvt_x fusion, mw=w*dinv[src] precompute (shortens
// aggregate dep chain), 8-deep gather unroll in aggregate.
// ---------------------------------------------------------------------------

#define HID 128

typedef __attribute__((ext_vector_type(8))) short bf16x8;
typedef __attribute__((ext_vector_type(4))) float f32x4;

__device__ __forceinline__ unsigned short f2bf(float f) {
    unsigned int u = __float_as_uint(f);
    u = (u + 0x7fff + ((u >> 16) & 1)) >> 16;   // round-to-nearest-even
    return (unsigned short)u;
}
__device__ __forceinline__ float bfu2f(unsigned int lo16) {  // low 16 bits = bf16
    return __uint_as_float(lo16 << 16);
}

// ---- fused count + x->bf16 conversion -------------------------------------
// Blocks 0..cvtBlocks-1 each convert 2048 floats; blocks 0..countBlocks-1
// also process one 256-edge chunk (1 atomic/thread). Atomic latency hides
// under the BW-bound conversion streams.
__global__ __launch_bounds__(256) void count_cvt_kernel(
        const int* __restrict__ dst, int* __restrict__ count,
        int* __restrict__ lpos, int E,
        const float* __restrict__ x, unsigned int* __restrict__ xb, long total8) {
    long g = (long)blockIdx.x * 256 + threadIdx.x;
    bool docvt = g < total8;
    float4 a, b;
    if (docvt) {
        const float4* p = reinterpret_cast<const float4*>(x + g * 8);
        a = p[0]; b = p[1];
    }
    int e = blockIdx.x * 256 + threadIdx.x;
    if (e < E) lpos[e] = atomicAdd(&count[dst[e]], 1);
    if (docvt) {
        uint4 o;
        o.x = (unsigned int)f2bf(a.x) | ((unsigned int)f2bf(a.y) << 16);
        o.y = (unsigned int)f2bf(a.z) | ((unsigned int)f2bf(a.w) << 16);
        o.z = (unsigned int)f2bf(b.x) | ((unsigned int)f2bf(b.y) << 16);
        o.w = (unsigned int)f2bf(b.z) | ((unsigned int)f2bf(b.w) << 16);
        *reinterpret_cast<uint4*>(xb + g * 4) = o;
    }
}

// W[k][128] fp32 -> Wt[128][K] bf16 for both layers in one launch.
__global__ __launch_bounds__(256) void cvt_wt_kernel(const float* __restrict__ W1,
                                                     unsigned short* __restrict__ Wt1, int K1,
                                                     const float* __restrict__ W2,
                                                     unsigned short* __restrict__ Wt2, int K2) {
    int t = blockIdx.x * 256 + threadIdx.x;
    int n1 = 128 * K1;
    if (t < n1) {
        int k = t % K1, c = t / K1;
        Wt1[c * K1 + k] = f2bf(W1[(size_t)k * 128 + c]);
        return;
    }
    t -= n1;
    if (t < 128 * K2) {
        int k = t % K2, c = t / K2;
        Wt2[c * K2 + k] = f2bf(W2[(size_t)k * 128 + c]);
    }
}

// ---- CSR build ------------------------------------------------------------

__global__ __launch_bounds__(256) void init_kernel(int* count, int n) {
    int i = blockIdx.x * 256 + threadIdx.x;
    if (i < n) count[i] = 0;
}

__global__ __launch_bounds__(1024) void scan1_kernel(const int* __restrict__ count,
                                                     int* __restrict__ row_start,
                                                     int* __restrict__ partials, int n) {
    __shared__ int sdata[1024];
    int t = threadIdx.x;
    int gid = blockIdx.x * 1024 + t;
    int v = (gid < n) ? count[gid] : 0;
    sdata[t] = v;
    __syncthreads();
    for (int off = 1; off < 1024; off <<= 1) {
        int x = (t >= off) ? sdata[t - off] : 0;
        __syncthreads();
        sdata[t] += x;
        __syncthreads();
    }
    if (gid < n) row_start[gid] = sdata[t] - v;  // exclusive
    if (t == 1023) partials[blockIdx.x] = sdata[t];
}

__global__ __launch_bounds__(1024) void scan2_kernel(int* partials, int nparts) {
    __shared__ int sdata[1024];
    int t = threadIdx.x;
    int v = (t < nparts) ? partials[t] : 0;
    sdata[t] = v;
    __syncthreads();
    for (int off = 1; off < 1024; off <<= 1) {
        int x = (t >= off) ? sdata[t - off] : 0;
        __syncthreads();
        sdata[t] += x;
        __syncthreads();
    }
    if (t < nparts) partials[t] = sdata[t] - v;  // exclusive
}

__global__ __launch_bounds__(256) void finalize_kernel(const int* __restrict__ partials,
                                                       int* __restrict__ row_start,
                                                       int n, int E) {
    int i = blockIdx.x * 256 + threadIdx.x;
    if (i < n) row_start[i] += partials[i >> 10];
    if (i == 0) row_start[n] = E;
}

// Atomic-free scatter using saved local positions. Stores (src, raw w).
__global__ __launch_bounds__(256) void fill_kernel(const int* __restrict__ src,
                                                   const int* __restrict__ dst,
                                                   const float* __restrict__ w,
                                                   const int* __restrict__ row_start,
                                                   const int* __restrict__ lpos,
                                                   uint2* __restrict__ csr_sw, int E) {
    int e = blockIdx.x * 256 + threadIdx.x;
    if (e >= E) return;
    int d = dst[e];
    int pos = row_start[d] + lpos[e];
    csr_sw[pos] = make_uint2((unsigned int)src[e], __float_as_uint(w[e]));
}

__global__ __launch_bounds__(256) void dinv_kernel(const uint2* __restrict__ csr_sw,
                                                   const int* __restrict__ row_start,
                                                   float* __restrict__ dinv, int n) {
    int i = blockIdx.x * 256 + threadIdx.x;
    if (i >= n) return;
    float dsum = 1.0f;
    int e1 = row_start[i + 1];
    for (int e = row_start[i]; e < e1; e++) dsum += __uint_as_float(csr_sw[e].y);
    dinv[i] = rsqrtf(dsum);
}

// In-place: csr.y <- w * dinv[src]. Removes the dinv gather from aggregate.
__global__ __launch_bounds__(256) void mw_kernel(uint2* __restrict__ csr_sw,
                                                 const float* __restrict__ dinv, int E) {
    int e = blockIdx.x * 256 + threadIdx.x;
    if (e >= E) return;
    uint2 v = csr_sw[e];
    v.y = __float_as_uint(__uint_as_float(v.y) * dinv[v.x]);
    csr_sw[e] = v;
}

// ---------------------------------------------------------------------------
// MFMA GEMM: Hb[n][128] = Ab[n][K] @ Wt^T, bf16 in / fp32 accum / bf16 out.
// Tile 128x128, BK=32, 4 waves, 2x8 16x16x32 frags per wave.
// ---------------------------------------------------------------------------
template <int K>
__global__ __launch_bounds__(256) void gemm_mfma_kernel(
        const unsigned short* __restrict__ Ab,   // [n][K] bf16
        const unsigned short* __restrict__ Wt,   // [128][K] bf16 (transposed W)
        unsigned short* __restrict__ Hb,         // [n][128] bf16
        int n) {
    __shared__ unsigned short Asl[128][40];   // 32 bf16 + pad to 40
    __shared__ unsigned short Btl[128][40];
    const int t = threadIdx.x;
    const int w = t >> 6;
    const int l = t & 63;
    const int lr = l & 15;
    const int ks = l >> 4;          // 0..3
    const int brow = blockIdx.x * 128;

    f32x4 acc[2][8];
#pragma unroll
    for (int m = 0; m < 2; m++)
#pragma unroll
        for (int j = 0; j < 8; j++) acc[m][j] = (f32x4)(0.f);

    for (int k0 = 0; k0 < K; k0 += 32) {
#pragma unroll
        for (int i = 0; i < 2; i++) {
            int idx = i * 256 + t;
            int r = idx >> 2;
            int c8 = idx & 3;
            int gr = brow + r;
            uint4 v = make_uint4(0u, 0u, 0u, 0u);
            if (gr < n) v = *reinterpret_cast<const uint4*>(&Ab[(size_t)gr * K + k0 + c8 * 8]);
            *reinterpret_cast<uint4*>(&Asl[r][c8 * 8]) = v;
        }
#pragma unroll
        for (int i = 0; i < 2; i++) {
            int idx = i * 256 + t;
            int r = idx >> 2;
            int c8 = idx & 3;
            uint4 v = *reinterpret_cast<const uint4*>(&Wt[(size_t)r * K + k0 + c8 * 8]);
            *reinterpret_cast<uint4*>(&Btl[r][c8 * 8]) = v;
        }
        __syncthreads();

        bf16x8 af[2];
#pragma unroll
        for (int m = 0; m < 2; m++)
            af[m] = *reinterpret_cast<const bf16x8*>(&Asl[w * 32 + m * 16 + lr][ks * 8]);
#pragma unroll
        for (int j = 0; j < 8; j++) {
            bf16x8 bfr = *reinterpret_cast<const bf16x8*>(&Btl[j * 16 + lr][ks * 8]);
            acc[0][j] = __builtin_amdgcn_mfma_f32_16x16x32_bf16(af[0], bfr, acc[0][j], 0, 0, 0);
            acc[1][j] = __builtin_amdgcn_mfma_f32_16x16x32_bf16(af[1], bfr, acc[1][j], 0, 0, 0);
        }
        __syncthreads();
    }

#pragma unroll
    for (int m = 0; m < 2; m++) {
#pragma unroll
        for (int r = 0; r < 4; r++) {
            int row = brow + w * 32 + m * 16 + ks * 4 + r;
            if (row < n) {
#pragma unroll
                for (int j = 0; j < 8; j++)
                    Hb[(size_t)row * 128 + j * 16 + lr] = f2bf(acc[m][j][r]);
            }
        }
    }
}

// ---------------------------------------------------------------------------
// Aggregate + bias + erf-GELU. One wave per node; lane c2 owns dims
// {2*c2, 2*c2+1}. csr entries hold (src, mw=w*dinv[src]) -> inner loop is
// pure {uniform csr load, hb gather, 2 fma}. 8-deep unroll for MLP.
//   out = gelu(b + dinv^2*h_self + dinv * sum mw_e*h[src_e])
// ---------------------------------------------------------------------------
template <bool BF16_OUT>
__global__ __launch_bounds__(256) void aggregate_gelu_kernel(
        const unsigned int* __restrict__ hb,   // bf16 pairs, [n][64]
        const int* __restrict__ row_start,
        const uint2* __restrict__ csr_sw,      // (src, mw)
        const float* __restrict__ dinv,
        const float* __restrict__ bias,
        unsigned int* __restrict__ outb,
        float* __restrict__ outf, int n) {
    int node = blockIdx.x * 4 + (threadIdx.x >> 6);
    int c2 = threadIdx.x & 63;
    if (node >= n) return;

    float di = dinv[node];
    float dd = di * di;
    float2 b2 = *reinterpret_cast<const float2*>(&bias[c2 * 2]);
    unsigned int self = hb[(size_t)node * 64 + c2];
    float s0 = 0.f, s1 = 0.f;

    int e = row_start[node];
    const int e1 = row_start[node + 1];

    for (; e + 8 <= e1; e += 8) {
        uint2 ew[8];
#pragma unroll
        for (int i = 0; i < 8; i++) ew[i] = csr_sw[e + i];
        unsigned int v[8];
#pragma unroll
        for (int i = 0; i < 8; i++) v[i] = hb[(size_t)ew[i].x * 64 + c2];
#pragma unroll
        for (int i = 0; i < 8; i++) {
            float m = __uint_as_float(ew[i].y);
            s0 += m * bfu2f(v[i] & 0xffffu);
            s1 += m * bfu2f(v[i] >> 16);
        }
    }
    if (e + 4 <= e1) {
        uint2 ew[4];
#pragma unroll
        for (int i = 0; i < 4; i++) ew[i] = csr_sw[e + i];
        unsigned int v[4];
#pragma unroll
        for (int i = 0; i < 4; i++) v[i] = hb[(size_t)ew[i].x * 64 + c2];
#pragma unroll
        for (int i = 0; i < 4; i++) {
            float m = __uint_as_float(ew[i].y);
            s0 += m * bfu2f(v[i] & 0xffffu);
            s1 += m * bfu2f(v[i] >> 16);
        }
        e += 4;
    }
    for (; e < e1; e++) {
        uint2 ew = csr_sw[e];
        float m = __uint_as_float(ew.y);
        unsigned int v = hb[(size_t)ew.x * 64 + c2];
        s0 += m * bfu2f(v & 0xffffu);
        s1 += m * bfu2f(v >> 16);
    }

    float acc0 = b2.x + dd * bfu2f(self & 0xffffu) + di * s0;
    float acc1 = b2.y + dd * bfu2f(self >> 16) + di * s1;
    float g0 = 0.5f * acc0 * (1.0f + erff(acc0 * 0.70710678118654752f));
    float g1 = 0.5f * acc1 * (1.0f + erff(acc1 * 0.70710678118654752f));
    if (BF16_OUT) {
        outb[(size_t)node * 64 + c2] =
            (unsigned int)f2bf(g0) | ((unsigned int)f2bf(g1) << 16);
    } else {
        *reinterpret_cast<float2*>(&outf[(size_t)node * 128 + c2 * 2]) = make_float2(g0, g1);
    }
}

// ---------------------------------------------------------------------------

extern "C" void kernel_launch(void* const* d_in, const int* in_sizes, int n_in,
                              void* d_out, int out_size, void* d_ws, size_t ws_size,
                              hipStream_t stream) {
    const float* x  = (const float*)d_in[0];
    const int*   ei = (const int*)d_in[1];
    const float* ew = (const float*)d_in[2];
    const float* W1 = (const float*)d_in[3];
    const float* b1 = (const float*)d_in[4];
    const float* W2 = (const float*)d_in[5];
    const float* b2 = (const float*)d_in[6];

    const int IN = 256;
    const int n = in_sizes[0] / IN;
    const int E = in_sizes[2];
    const int* src = ei;
    const int* dst = ei + E;

    char* wsb = (char*)d_ws;
    size_t off = 0;
    auto alloc = [&](size_t bytes) -> void* {
        void* p = wsb + off;
        off = (off + bytes + 255) & ~(size_t)255;
        return p;
    };
    int*   count     = (int*)alloc((size_t)n * 4);
    int*   lpos      = (int*)alloc((size_t)E * 4);
    int*   row_start = (int*)alloc((size_t)(n + 1) * 4);
    int*   partials  = (int*)alloc(4096);
    float* dinv      = (float*)alloc((size_t)n * 4);
    uint2* csr_sw    = (uint2*)alloc((size_t)E * 8);
    unsigned short* hb  = (unsigned short*)alloc((size_t)n * HID * 2);  // bf16 h
    unsigned short* wt1 = (unsigned short*)alloc((size_t)128 * IN * 2);
    unsigned short* wt2 = (unsigned short*)alloc((size_t)128 * HID * 2);

    // xb (bf16 x) and act1b (bf16 act1) live inside d_out (see round 5 note).
    unsigned short* xb    = (unsigned short*)d_out;
    unsigned short* act1b = (unsigned short*)d_out;
    float* out = (float*)d_out;

    const int nscan = (n + 1023) / 1024;
    long total8 = (long)n * IN / 8;
    int cvtBlocks = (int)((total8 + 255) / 256);
    int fusedBlocks = cvtBlocks > (E + 255) / 256 ? cvtBlocks : (E + 255) / 256;

    hipLaunchKernelGGL(init_kernel, dim3((n + 255) / 256), dim3(256), 0, stream, count, n);
    hipLaunchKernelGGL(count_cvt_kernel, dim3(fusedBlocks), dim3(256), 0, stream,
                       dst, count, lpos, E, x, (unsigned int*)xb, total8);
    hipLaunchKernelGGL(cvt_wt_kernel, dim3((128 * IN + 128 * HID + 255) / 256), dim3(256),
                       0, stream, W1, wt1, IN, W2, wt2, HID);
    hipLaunchKernelGGL(scan1_kernel, dim3(nscan), dim3(1024), 0, stream,
                       count, row_start, partials, n);
    hipLaunchKernelGGL(scan2_kernel, dim3(1), dim3(1024), 0, stream, partials, nscan);
    hipLaunchKernelGGL(finalize_kernel, dim3((n + 255) / 256), dim3(256), 0, stream,
                       partials, row_start, n, E);
    hipLaunchKernelGGL(fill_kernel, dim3((E + 255) / 256), dim3(256), 0, stream,
                       src, dst, ew, row_start, lpos, csr_sw, E);
    hipLaunchKernelGGL(dinv_kernel, dim3((n + 255) / 256), dim3(256), 0, stream,
                       csr_sw, row_start, dinv, n);
    hipLaunchKernelGGL(mw_kernel, dim3((E + 255) / 256), dim3(256), 0, stream,
                       csr_sw, dinv, E);

    // layer 1: mfma gemm (xb -> hb) ; aggregate -> act1b (bf16, in d_out)
    hipLaunchKernelGGL((gemm_mfma_kernel<256>), dim3((n + 127) / 128), dim3(256), 0, stream,
                       xb, wt1, hb, n);
    hipLaunchKernelGGL((aggregate_gelu_kernel<true>), dim3((n + 3) / 4), dim3(256), 0, stream,
                       (const unsigned int*)hb, row_start, csr_sw, dinv, b1,
                       (unsigned int*)act1b, nullptr, n);
    // layer 2: mfma gemm (act1b -> hb) ; aggregate -> out (fp32)
    hipLaunchKernelGGL((gemm_mfma_kernel<128>), dim3((n + 127) / 128), dim3(256), 0, stream,
                       act1b, wt2, hb, n);
    hipLaunchKernelGGL((aggregate_gelu_kernel<false>), dim3((n + 3) / 4), dim3(256), 0, stream,
                       (const unsigned int*)hb, row_start, csr_sw, dinv, b2,
                       nullptr, out, n);
}